// Round 10
// baseline (254.970 us; speedup 1.0000x reference)
//
#include <hip/hip_runtime.h>
#include <hip/hip_bf16.h>

// ---------------------------------------------------------------------------
// DeformableSpatialEncoder on MI355X (gfx950)
//
// Pipeline (N=64 images, Lq=196 tokens, D=768, heads=4, Dh=192, points=4):
//   0. prep:   WeT bf16 = embed_w^T; Wcat_b bf16 concat; bcat2; zero core.
//   1. stage:  blocks [0,42):   LDS-free fold-GEMM Wc[896,768] = Wcat_b @ WeT^T
//              blocks [42,9450): im2col x -> A bf16 [12544,768]
//      Folding identity: cat = (A@We^T+be)@Wcat^T+bcat = A@(Wcat·We)^T + (...)
//   2. gemm2:  value -> Vbuf bf16; off/aw -> OA f32. 64x128 tile (R9: 128x128
//              gave 686 blocks = 2.7/CU, occupancy 27%, MfmaUtil 12.5% --
//              grid-limited; 64x128 doubles blocks to 1372 = 5.4/CU) +
//              XCD-chunked swizzle (R7->R9: FETCH 71MB->ok, gemm2 50.5->
//              <40us; kept).
//   3. deform: 192-thread blocks, grid (64,49); thread owns 4 consecutive
//              channels, bf16x4 corner loads (R9 theory: old version did 64
//              scalar 2B loads/thread = 128B/wave-instr; now 512B/wave-instr,
//              4x fewer load instructions).
//   4. pooled = core_mean @ outp_w^T + outp_b
//   5. final  = pooled @ proj_w^T + proj_b -> d_out
//      4/5 use small_linear_ks (R7: confirmed fix).
// ---------------------------------------------------------------------------

using bf16 = __bf16;
typedef bf16  bf16x4 __attribute__((ext_vector_type(4)));
typedef bf16  bf16x8 __attribute__((ext_vector_type(8)));
typedef float f32x4  __attribute__((ext_vector_type(4)));

#define N_IMG   64
#define LQ      196
#define DM      768
#define NH      4
#define DH      192
#define M_ROWS  (N_IMG * LQ)        // 12544
#define NCAT    896                 // 768 value + 32 off + 16 aw + 80 pad

// prep grid layout
#define P_WET    0                  // 288 blocks: WeT transpose-cast
#define P_WCAT   288                // 336 blocks: Wcat_b cast/concat
#define P_BCAT   624                // 4 blocks
#define P_ZERO   628                // 48 blocks
#define PREP_GRID 676

// stage grid layout
#define B_WGEMM   0                 // 42 blocks: 7 (o-tiles) x 6 (e-tiles)
#define B_IM2COL  42                // 9408 blocks
#define STAGE_GRID (B_IM2COL + 9408)

// ---- workspace layout (bytes, all 256-aligned) ----
#define OFF_A     ((size_t)0)                      // 12544*768*2 = 19267584
#define OFF_WC    (OFF_A     + 19267584)           // 896*768*2   = 1376256
#define OFF_BCAT  (OFF_WC    + 1376256)            // 4096
#define OFF_VBUF  (OFF_BCAT  + 4096)               // 12544*768*2 = 19267584
#define OFF_OA    (OFF_VBUF  + 19267584)           // 12544*64*4  = 3211264
#define OFF_CORE  (OFF_OA    + 3211264)            // 196608
#define OFF_POOL  (OFF_CORE  + 196608)             // 196608
#define OFF_WCATB (OFF_POOL  + 196608)             // 896*768*2   = 1376256
#define OFF_WET   (OFF_WCATB + 1376256)            // 768*768*2   = 1179648

__device__ __forceinline__ void gload_lds16(const bf16* g, bf16* l) {
#if __has_builtin(__builtin_amdgcn_global_load_lds)
  __builtin_amdgcn_global_load_lds(
      (const __attribute__((address_space(1))) void*)g,
      (__attribute__((address_space(3))) void*)l, 16, 0, 0);
#else
  *(bf16x8*)l = *(const bf16x8*)g;
#endif
}

// ---------------------------------------------------------------------------
// prep: WeT transpose-cast, Wcat_b cast, bcat2, core zero.
// ---------------------------------------------------------------------------
__global__ void prep_kernel(const float* __restrict__ embed_w,
                            const float* __restrict__ embed_b,
                            const float* __restrict__ value_w,
                            const float* __restrict__ off_w,
                            const float* __restrict__ aw_w,
                            const float* __restrict__ value_b,
                            const float* __restrict__ off_b,
                            const float* __restrict__ aw_b,
                            bf16* __restrict__ WeT,
                            bf16* __restrict__ Wcatb,
                            float* __restrict__ bcat2,
                            float* __restrict__ core) {
  const int bid = blockIdx.x;
  const int tid = threadIdx.x;

  if (bid < P_WCAT) {                    // ---- WeT[e][d] = embed_w[d][e] ----
    const int t = bid * 256 + tid;       // < 73728 exactly (288*256)
    const int e = t / 96;
    const int g = t - e * 96;            // d-group of 8
    bf16x8 o;
#pragma unroll
    for (int j = 0; j < 8; ++j)
      o[j] = (bf16)embed_w[(size_t)(g * 8 + j) * DM + e];
    *(bf16x8*)(WeT + (size_t)e * DM + g * 8) = o;
    return;
  }

  if (bid < P_BCAT) {                    // ---- Wcat_b cast/concat ----
    const int t = (bid - P_WCAT) * 256 + tid;   // < 86016 exactly (336*256)
    const int rr = t / 96;
    const int g  = t - rr * 96;
    const float* src = (rr < 768) ? value_w + (size_t)rr * DM
                     : (rr < 800) ? off_w + (size_t)(rr - 768) * DM
                     : (rr < 816) ? aw_w + (size_t)(rr - 800) * DM : nullptr;
    bf16x8 o;
    if (src) {
      const float4 f0 = *(const float4*)(src + g * 8);
      const float4 f1 = *(const float4*)(src + g * 8 + 4);
      o[0] = (bf16)f0.x; o[1] = (bf16)f0.y; o[2] = (bf16)f0.z; o[3] = (bf16)f0.w;
      o[4] = (bf16)f1.x; o[5] = (bf16)f1.y; o[6] = (bf16)f1.z; o[7] = (bf16)f1.w;
    } else {
#pragma unroll
      for (int j = 0; j < 8; ++j) o[j] = (bf16)0.f;
    }
    *(bf16x8*)(Wcatb + (size_t)rr * DM + g * 8) = o;
    return;
  }

  if (bid < P_ZERO) {                    // ---- bcat2 = Wcat @ embed_b + bias ----
    const int o = (bid - P_BCAT) * 256 + tid;   // 0..1023
    if (o < NCAT) {
      float bias_o = (o < 768) ? value_b[o]
                   : (o < 800) ? off_b[o - 768]
                   : (o < 816) ? aw_b[o - 800] : 0.f;
      float acc = 0.f;
      if (o < 816) {
        const float* wr = (o < 768) ? value_w + (size_t)o * DM
                        : (o < 800) ? off_w + (size_t)(o - 768) * DM
                        : aw_w + (size_t)(o - 800) * DM;
        const float4* w4p = (const float4*)wr;
        const float4* b4p = (const float4*)embed_b;
#pragma unroll 4
        for (int k = 0; k < DM / 4; ++k) {
          const float4 wv = w4p[k], bv = b4p[k];
          acc += wv.x * bv.x + wv.y * bv.y + wv.z * bv.z + wv.w * bv.w;
        }
      }
      bcat2[o] = acc + bias_o;
    }
    return;
  }

  // ---- zero core ----
  const int i = (bid - P_ZERO) * 256 + tid;
  f32x4 z = {0.f, 0.f, 0.f, 0.f};
  ((f32x4*)core)[i] = z;
}

// ---------------------------------------------------------------------------
// stage: NO __shared__ (im2col occupancy stays wave-limited at 8 blocks/CU).
// blocks [0,42):    fold-GEMM Wc = Wcat_b @ WeT^T via register MFMA fragments
// blocks [42,9450): im2col, one thread = 4 consecutive k of one row.
// ---------------------------------------------------------------------------
__global__ void stage_kernel(const float* __restrict__ x,
                             const bf16* __restrict__ Wcatb,
                             const bf16* __restrict__ WeT,
                             bf16* __restrict__ A,
                             bf16* __restrict__ Wc) {
  const int bid = blockIdx.x;
  const int tid = threadIdx.x;

  if (bid >= B_IM2COL) {                 // ---- im2col ----
    const int t   = (bid - B_IM2COL) * 256 + tid;  // < 12544*192 exactly
    const int row = t / 192;
    const int j   = t - row * 192;
    const int k   = j * 4;               // k = c*256 + p*16 + q, q%4==0
    const int c   = k >> 8;
    const int r   = k & 255;
    const int p   = r >> 4;
    const int q   = r & 15;
    const int n   = row / 196;
    const int lq  = row - n * 196;
    const int h   = lq / 14;
    const int w   = lq - h * 14;
    const float4 v = *(const float4*)(x +
        ((((size_t)n * 3 + c) * 224) + h * 16 + p) * 224 + w * 16 + q);
    bf16x4 o;
    o[0] = (bf16)v.x; o[1] = (bf16)v.y; o[2] = (bf16)v.z; o[3] = (bf16)v.w;
    *(bf16x4*)(A + (size_t)row * DM + k) = o;
    return;
  }

  // ---- fold-GEMM: Wc[o,e] = sum_d Wcat_b[o,d] * WeT[e,d] ----
  const int mT = bid / 6;                // 0..6  o-tile
  const int nT = bid - mT * 6;           // 0..5  e-tile
  const int oBase = mT * 128;
  const int eBase = nT * 128;
  const int wave = tid >> 6;
  const int lane = tid & 63;
  const int quad = lane >> 4;
  const int r16  = lane & 15;
  const int wm = wave & 1;
  const int wn = wave >> 1;

  const f32x4 zero = {0.f, 0.f, 0.f, 0.f};
  f32x4 acc[4][4];
#pragma unroll
  for (int mi = 0; mi < 4; ++mi)
#pragma unroll
    for (int ni = 0; ni < 4; ++ni) acc[mi][ni] = zero;

  const bf16* Ab = Wcatb + (size_t)(oBase + wm * 64 + r16) * DM + quad * 8;
  const bf16* Bb = WeT   + (size_t)(eBase + wn * 64 + r16) * DM + quad * 8;

#pragma unroll 2
  for (int kk = 0; kk < DM; kk += 32) {
    bf16x8 af[4], bfr[4];
#pragma unroll
    for (int mi = 0; mi < 4; ++mi)
      af[mi] = *(const bf16x8*)(Ab + (size_t)mi * 16 * DM + kk);
#pragma unroll
    for (int ni = 0; ni < 4; ++ni)
      bfr[ni] = *(const bf16x8*)(Bb + (size_t)ni * 16 * DM + kk);
#pragma unroll
    for (int mi = 0; mi < 4; ++mi)
#pragma unroll
      for (int ni = 0; ni < 4; ++ni)
        acc[mi][ni] = __builtin_amdgcn_mfma_f32_16x16x32_bf16(
            af[mi], bfr[ni], acc[mi][ni], 0, 0, 0);
  }

#pragma unroll
  for (int ni = 0; ni < 4; ++ni) {
    const int col = eBase + wn * 64 + ni * 16 + r16;
#pragma unroll
    for (int mi = 0; mi < 4; ++mi) {
      const int row0 = oBase + wm * 64 + mi * 16 + quad * 4;
#pragma unroll
      for (int rr = 0; rr < 4; ++rr)
        Wc[(size_t)(row0 + rr) * DM + col] = (bf16)acc[mi][ni][rr];
    }
  }
}

// ---------------------------------------------------------------------------
// gemm2_mixed: C = A[M,K]bf16 @ B[N,K]bf16^T + bias; epilogue splits columns:
//   col <  768 -> Vbuf bf16 [M,768];  col < 816 -> OA f32 [M,64];  else drop.
// 64x128 tile, BK=64, 256 threads (2x2 waves of 32x64), acc[2][4].
// R9: 128x128 was grid-limited (686 blocks = 2.7/CU, occ 27%, MfmaUtil 12.5%);
// 64x128 -> 1372 blocks = 5.4/CU, LDS 24KB.
// XCD-chunked bijective swizzle (m204): each XCD owns a contiguous n-fast
// range so the 7 n-tiles of an A m-tile share one XCD L2 (R7 fix, kept).
// ---------------------------------------------------------------------------
__global__ void gemm2_mixed(const bf16* __restrict__ A, const bf16* __restrict__ B,
                            const float* __restrict__ bias,
                            bf16* __restrict__ Vb, float* __restrict__ OA,
                            int M, int N, int K) {
  __shared__ bf16 As[64 * 64];
  __shared__ bf16 Bs[128 * 64];

  const int tid  = threadIdx.x;
  const int wave = tid >> 6;
  const int lane = tid & 63;

  // ---- XCD-chunked swizzle (bijective for any nwg) ----
  const int p   = blockIdx.y * gridDim.x + blockIdx.x;   // physical linear id
  const int nwg = gridDim.x * gridDim.y;
  const int q   = nwg >> 3;
  const int r   = nwg & 7;
  const int xcd = p & 7;                 // HW round-robins workgroups % 8 XCDs
  const int jj  = p >> 3;
  const int L   = (xcd < r ? xcd * (q + 1) : r * (q + 1) + (xcd - r) * q) + jj;
  const int nT  = L % gridDim.x;         // n-fast: consecutive L share an A-tile
  const int mT  = L / gridDim.x;
  const int nBase = nT * 128;
  const int mBase = mT * 64;

  const int wm = wave & 1;               // m half (32 rows)
  const int wn = wave >> 1;              // n half (64 cols)
  const int quad = lane >> 4;
  const int r16  = lane & 15;

  const f32x4 zero = {0.f, 0.f, 0.f, 0.f};
  f32x4 acc[2][4];
#pragma unroll
  for (int mi = 0; mi < 2; ++mi)
#pragma unroll
    for (int ni = 0; ni < 4; ++ni) acc[mi][ni] = zero;

  const int sr = tid >> 3;               // 0..31
  const int sc = (tid & 7) * 8;          // 0..56
  const bf16* Ag = A + (size_t)(mBase + sr) * K + sc;
  const bf16* Bg = B + (size_t)(nBase + sr) * K + sc;
  bf16* Al = As + sr * 64 + sc;
  bf16* Bl = Bs + sr * 64 + sc;

  for (int kt = 0; kt < K; kt += 64) {
#pragma unroll
    for (int i = 0; i < 2; ++i)          // A: 64 rows, 2 rounds of 32
      gload_lds16(Ag + (size_t)(i * 32) * K + kt, Al + i * 32 * 64);
#pragma unroll
    for (int i = 0; i < 4; ++i)          // B: 128 rows, 4 rounds of 32
      gload_lds16(Bg + (size_t)(i * 32) * K + kt, Bl + i * 32 * 64);
    __syncthreads();
#pragma unroll
    for (int kk = 0; kk < 64; kk += 32) {
      bf16x8 af[2], bfr[4];
#pragma unroll
      for (int mi = 0; mi < 2; ++mi)
        af[mi] = *(const bf16x8*)&As[(wm * 32 + mi * 16 + r16) * 64 + kk + quad * 8];
#pragma unroll
      for (int ni = 0; ni < 4; ++ni)
        bfr[ni] = *(const bf16x8*)&Bs[(wn * 64 + ni * 16 + r16) * 64 + kk + quad * 8];
#pragma unroll
      for (int mi = 0; mi < 2; ++mi)
#pragma unroll
        for (int ni = 0; ni < 4; ++ni)
          acc[mi][ni] = __builtin_amdgcn_mfma_f32_16x16x32_bf16(
              af[mi], bfr[ni], acc[mi][ni], 0, 0, 0);
    }
    __syncthreads();
  }

  // epilogue: C row = quad*4 + reg, col = lane&15 (m89/m91-verified layout)
#pragma unroll
  for (int ni = 0; ni < 4; ++ni) {
    const int col = nBase + wn * 64 + ni * 16 + r16;
    const float bv = bias[col];
#pragma unroll
    for (int mi = 0; mi < 2; ++mi) {
      const int row0 = mBase + wm * 32 + mi * 16 + quad * 4;
#pragma unroll
      for (int rr = 0; rr < 4; ++rr) {
        float v = acc[mi][ni][rr] + bv;
        int row = row0 + rr;
        if (col < 768) {
          Vb[(size_t)row * 768 + col] = (bf16)v;
        } else if (col < 816) {
          OA[(size_t)row * 64 + (col - 768)] = v;
        }
      }
    }
  }
}

// ---------------------------------------------------------------------------
// deform: grid (64, 49), block 192 (3 waves).
// Phase 1 (64 threads): per (lq_i, head, point) compute 4 combined
//   softmax*bilinear*validity weights + 4 clamped token indices -> LDS.
// Phase 2 (192 threads): thread = 4 consecutive channels (same head since
//   DH=192 is a multiple of 4 and head boundaries are multiples of 48 threads)
//   -> 64 bf16x4 (8B) gathers per thread; a wave-load now moves 512B
//   contiguous vs 128B for the old scalar-bf16 version (4x fewer load
//   instructions, same total bytes; per-channel summation order unchanged).
// ---------------------------------------------------------------------------
__global__ void deform_kernel(const bf16* __restrict__ Vb,
                              const float* __restrict__ OA,
                              float* __restrict__ core) {
  __shared__ float s_w[64][4];
  __shared__ int   s_t[64][4];

  const int n   = blockIdx.x;
  const int lq0 = blockIdx.y * 4;
  const int tid = threadIdx.x;

  if (tid < 64) {
    const int i = tid >> 4;          // lq within group
    const int m = (tid >> 2) & 3;    // head
    const int p = tid & 3;           // point
    const int lq = lq0 + i;
    const float* row = OA + ((size_t)n * LQ + lq) * 64;

    const float l0 = row[32 + m * 4 + 0];
    const float l1 = row[32 + m * 4 + 1];
    const float l2 = row[32 + m * 4 + 2];
    const float l3 = row[32 + m * 4 + 3];
    const float mx = fmaxf(fmaxf(l0, l1), fmaxf(l2, l3));
    const float e0 = __expf(l0 - mx), e1 = __expf(l1 - mx);
    const float e2 = __expf(l2 - mx), e3 = __expf(l3 - mx);
    const float inv = 1.f / (e0 + e1 + e2 + e3);
    const float ep[4] = {e0, e1, e2, e3};
    const float ew = ep[p] * inv;

    const int h = lq / 14, w = lq - (lq / 14) * 14;
    // px = w*14/13 + offx - 0.5  (ref linspace(0,1,14), normalizer W=14)
    const float px = (float)w * (14.f / 13.f) - 0.5f + row[(m * 4 + p) * 2 + 0];
    const float py = (float)h * (14.f / 13.f) - 0.5f + row[(m * 4 + p) * 2 + 1];
    const float fx = floorf(px), fy = floorf(py);
    const int x0 = (int)fx, y0 = (int)fy;
    const float wx1 = px - fx, wy1 = py - fy;
    const float wx0 = 1.f - wx1, wy0 = 1.f - wy1;

    const bool vx0 = (x0 >= 0) & (x0 < 14);
    const bool vx1 = (x0 >= -1) & (x0 < 13);
    const bool vy0 = (y0 >= 0) & (y0 < 14);
    const bool vy1 = (y0 >= -1) & (y0 < 13);
    const int cx0 = min(max(x0, 0), 13),      cx1 = min(max(x0 + 1, 0), 13);
    const int cy0 = min(max(y0, 0), 13) * 14, cy1 = min(max(y0 + 1, 0), 13) * 14;

    s_w[tid][0] = (vx0 & vy0) ? ew * wx0 * wy0 : 0.f;
    s_w[tid][1] = (vx1 & vy0) ? ew * wx1 * wy0 : 0.f;
    s_w[tid][2] = (vx0 & vy1) ? ew * wx0 * wy1 : 0.f;
    s_w[tid][3] = (vx1 & vy1) ? ew * wx1 * wy1 : 0.f;
    s_t[tid][0] = cy0 + cx0;
    s_t[tid][1] = cy0 + cx1;
    s_t[tid][2] = cy1 + cx0;
    s_t[tid][3] = cy1 + cx1;
  }
  __syncthreads();

  const int ch = tid * 4;           // 0..764, 4 consecutive channels
  const int m  = tid / 48;          // head (uniform per 48-thread group)
  const bf16* vb = Vb + (size_t)n * LQ * 768 + ch;
  float a0 = 0.f, a1 = 0.f, a2 = 0.f, a3 = 0.f;
#pragma unroll
  for (int i = 0; i < 4; ++i) {
#pragma unroll
    for (int p = 0; p < 4; ++p) {
      const int e = i * 16 + m * 4 + p;
      const float4 w4 = *(const float4*)s_w[e];
      const int4   t4 = *(const int4*)s_t[e];
      const bf16x4 v0 = *(const bf16x4*)(vb + (size_t)t4.x * 768);
      const bf16x4 v1 = *(const bf16x4*)(vb + (size_t)t4.y * 768);
      const bf16x4 v2 = *(const bf16x4*)(vb + (size_t)t4.z * 768);
      const bf16x4 v3 = *(const bf16x4*)(vb + (size_t)t4.w * 768);
      a0 += w4.x * (float)v0[0] + w4.y * (float)v1[0]
          + w4.z * (float)v2[0] + w4.w * (float)v3[0];
      a1 += w4.x * (float)v0[1] + w4.y * (float)v1[1]
          + w4.z * (float)v2[1] + w4.w * (float)v3[1];
      a2 += w4.x * (float)v0[2] + w4.y * (float)v1[2]
          + w4.z * (float)v2[2] + w4.w * (float)v3[2];
      a3 += w4.x * (float)v0[3] + w4.y * (float)v1[3]
          + w4.z * (float)v2[3] + w4.w * (float)v3[3];
    }
  }
  float* cp = core + (size_t)n * DM + ch;
  atomicAdd(cp + 0, a0 * (1.f / 196.f));
  atomicAdd(cp + 1, a1 * (1.f / 196.f));
  atomicAdd(cp + 2, a2 * (1.f / 196.f));
  atomicAdd(cp + 3, a3 * (1.f / 196.f));
}

// ---------------------------------------------------------------------------
// small_linear_ks: out[n][d] = sum_k in[n][k] * W[d][k] + b[d]
// grid (N_IMG/4, DM/64), block 256 = 4 waves. 4 images/block share W reads;
// K split across the 4 waves, LDS cross-wave reduce. (R7: confirmed fix.)
// ---------------------------------------------------------------------------
__global__ void small_linear_ks(const float* __restrict__ in,
                                const float* __restrict__ W,
                                const float* __restrict__ b,
                                float* __restrict__ out) {
  __shared__ float s_in[4 * DM];           // 12 KB
  __shared__ float s_red[3][4][64];        // 3 KB
  const int tid = threadIdx.x;
  const int n0 = blockIdx.x * 4;
  const float4* src = (const float4*)(in + (size_t)n0 * DM);
#pragma unroll
  for (int i = 0; i < 3; ++i)              // 4*768 floats = 768 float4
    ((float4*)s_in)[tid + i * 256] = src[tid + i * 256];
  __syncthreads();

  const int dl = tid & 63;
  const int ks = tid >> 6;                 // wave id = K-quarter
  const int d  = blockIdx.y * 64 + dl;
  const int k0 = ks * (DM / 4);            // 192 floats per wave

  const float4* w4p = (const float4*)(W + (size_t)d * DM + k0);
  const float4* s0 = (const float4*)(s_in + k0);
  const float4* s1 = (const float4*)(s_in + DM + k0);
  const float4* s2 = (const float4*)(s_in + 2 * DM + k0);
  const float4* s3 = (const float4*)(s_in + 3 * DM + k0);
  float a0 = 0.f, a1 = 0.f, a2 = 0.f, a3 = 0.f;
#pragma unroll 8
  for (int k = 0; k < DM / 16; ++k) {      // 48 float4 iterations
    const float4 w = w4p[k];
    const float4 v0 = s0[k], v1 = s1[k], v2 = s2[k], v3 = s3[k];
    a0 += w.x * v0.x + w.y * v0.y + w.z * v0.z + w.w * v0.w;
    a1 += w.x * v1.x + w.y * v1.y + w.z * v1.z + w.w * v1.w;
    a2 += w.x * v2.x + w.y * v2.y + w.z * v2.z + w.w * v2.w;
    a3 += w.x * v3.x + w.y * v3.y + w.z * v3.z + w.w * v3.w;
  }

  if (ks > 0) {
    s_red[ks - 1][0][dl] = a0;
    s_red[ks - 1][1][dl] = a1;
    s_red[ks - 1][2][dl] = a2;
    s_red[ks - 1][3][dl] = a3;
  }
  __syncthreads();
  if (ks == 0) {
#pragma unroll
    for (int w = 0; w < 3; ++w) {
      a0 += s_red[w][0][dl];
      a1 += s_red[w][1][dl];
      a2 += s_red[w][2][dl];
      a3 += s_red[w][3][dl];
    }
    const float bv = b[d];
    out[(size_t)(n0 + 0) * DM + d] = a0 + bv;
    out[(size_t)(n0 + 1) * DM + d] = a1 + bv;
    out[(size_t)(n0 + 2) * DM + d] = a2 + bv;
    out[(size_t)(n0 + 3) * DM + d] = a3 + bv;
  }
}

// ---------------------------------------------------------------------------
extern "C" void kernel_launch(void* const* d_in, const int* in_sizes, int n_in,
                              void* d_out, int out_size, void* d_ws, size_t ws_size,
                              hipStream_t stream) {
  const float* x       = (const float*)d_in[0];
  const float* embed_w = (const float*)d_in[1];
  const float* embed_b = (const float*)d_in[2];
  const float* value_w = (const float*)d_in[3];
  const float* value_b = (const float*)d_in[4];
  const float* off_w   = (const float*)d_in[5];
  const float* off_b   = (const float*)d_in[6];
  const float* aw_w    = (const float*)d_in[7];
  const float* aw_b    = (const float*)d_in[8];
  const float* outp_w  = (const float*)d_in[9];
  const float* outp_b  = (const float*)d_in[10];
  const float* proj_w  = (const float*)d_in[11];
  const float* proj_b  = (const float*)d_in[12];
  float* out = (float*)d_out;

  char* ws = (char*)d_ws;
  bf16*  A      = (bf16*)(ws + OFF_A);
  bf16*  Wc     = (bf16*)(ws + OFF_WC);
  float* bcat2  = (float*)(ws + OFF_BCAT);
  bf16*  Vbuf   = (bf16*)(ws + OFF_VBUF);
  float* OA     = (float*)(ws + OFF_OA);
  float* core   = (float*)(ws + OFF_CORE);
  float* pooled = (float*)(ws + OFF_POOL);
  bf16*  Wcatb  = (bf16*)(ws + OFF_WCATB);
  bf16*  WeT    = (bf16*)(ws + OFF_WET);

  prep_kernel<<<dim3(PREP_GRID), dim3(256), 0, stream>>>(
      embed_w, embed_b, value_w, off_w, aw_w, value_b, off_b, aw_b,
      WeT, Wcatb, bcat2, core);

  stage_kernel<<<dim3(STAGE_GRID), dim3(256), 0, stream>>>(
      x, Wcatb, WeT, A, Wc);

  gemm2_mixed<<<dim3(NCAT / 128, M_ROWS / 64), dim3(256), 0, stream>>>(
      A, Wc, bcat2, Vbuf, OA, M_ROWS, NCAT, DM);

  deform_kernel<<<dim3(N_IMG, 49), dim3(192), 0, stream>>>(Vbuf, OA, core);

  small_linear_ks<<<dim3(N_IMG / 4, DM / 64), dim3(256), 0, stream>>>(
      core, outp_w, outp_b, pooled);
  small_linear_ks<<<dim3(N_IMG / 4, DM / 64), dim3(256), 0, stream>>>(
      pooled, proj_w, proj_b, out);
}

// Round 13
// 246.737 us; speedup vs baseline: 1.0334x; 1.0334x over previous
//
#include <hip/hip_runtime.h>
#include <hip/hip_bf16.h>

// ---------------------------------------------------------------------------
// DeformableSpatialEncoder on MI355X (gfx950)
//
// Pipeline (N=64 images, Lq=196 tokens, D=768, heads=4, Dh=192, points=4):
//   0. prep:   WeT bf16 = embed_w^T; Wcat_b bf16 concat; bcat2; zero core.
//   1. stage:  blocks [0,42):   LDS-free fold-GEMM Wc[896,768] = Wcat_b @ WeT^T
//              blocks [42,9450): im2col x -> A bf16 [12544,768]
//      Folding identity: cat = (A@We^T+be)@Wcat^T+bcat = A@(Wcat·We)^T + (...)
//   2. gemm2:  value -> Vbuf bf16; off/aw -> OA f32.
//              128x128 tile + XCD-chunked swizzle == R9-exact version.
//              (R10: 64x128 regressed ~23us total -- halved MFMA per barrier
//              drain and +50% B staging traffic; reverted.)
//   3. deform: 192-thread blocks, grid (64,49); thread owns 4 consecutive
//              channels, bf16x4 corner loads (R10 change, KEPT -- mechanism
//              solid: 4x fewer load instrs, 512B/wave-instr; this round is
//              the A/B that isolates it).
//   4. pooled = core_mean @ outp_w^T + outp_b
//   5. final  = pooled @ proj_w^T + proj_b -> d_out
//      4/5 use small_linear_ks (R7: confirmed fix).
// ---------------------------------------------------------------------------

using bf16 = __bf16;
typedef bf16  bf16x4 __attribute__((ext_vector_type(4)));
typedef bf16  bf16x8 __attribute__((ext_vector_type(8)));
typedef float f32x4  __attribute__((ext_vector_type(4)));

#define N_IMG   64
#define LQ      196
#define DM      768
#define NH      4
#define DH      192
#define M_ROWS  (N_IMG * LQ)        // 12544
#define NCAT    896                 // 768 value + 32 off + 16 aw + 80 pad

// prep grid layout
#define P_WET    0                  // 288 blocks: WeT transpose-cast
#define P_WCAT   288                // 336 blocks: Wcat_b cast/concat
#define P_BCAT   624                // 4 blocks
#define P_ZERO   628                // 48 blocks
#define PREP_GRID 676

// stage grid layout
#define B_WGEMM   0                 // 42 blocks: 7 (o-tiles) x 6 (e-tiles)
#define B_IM2COL  42                // 9408 blocks
#define STAGE_GRID (B_IM2COL + 9408)

// ---- workspace layout (bytes, all 256-aligned) ----
#define OFF_A     ((size_t)0)                      // 12544*768*2 = 19267584
#define OFF_WC    (OFF_A     + 19267584)           // 896*768*2   = 1376256
#define OFF_BCAT  (OFF_WC    + 1376256)            // 4096
#define OFF_VBUF  (OFF_BCAT  + 4096)               // 12544*768*2 = 19267584
#define OFF_OA    (OFF_VBUF  + 19267584)           // 12544*64*4  = 3211264
#define OFF_CORE  (OFF_OA    + 3211264)            // 196608
#define OFF_POOL  (OFF_CORE  + 196608)             // 196608
#define OFF_WCATB (OFF_POOL  + 196608)             // 896*768*2   = 1376256
#define OFF_WET   (OFF_WCATB + 1376256)            // 768*768*2   = 1179648

__device__ __forceinline__ void gload_lds16(const bf16* g, bf16* l) {
#if __has_builtin(__builtin_amdgcn_global_load_lds)
  __builtin_amdgcn_global_load_lds(
      (const __attribute__((address_space(1))) void*)g,
      (__attribute__((address_space(3))) void*)l, 16, 0, 0);
#else
  *(bf16x8*)l = *(const bf16x8*)g;
#endif
}

// ---------------------------------------------------------------------------
// prep: WeT transpose-cast, Wcat_b cast, bcat2, core zero.
// ---------------------------------------------------------------------------
__global__ void prep_kernel(const float* __restrict__ embed_w,
                            const float* __restrict__ embed_b,
                            const float* __restrict__ value_w,
                            const float* __restrict__ off_w,
                            const float* __restrict__ aw_w,
                            const float* __restrict__ value_b,
                            const float* __restrict__ off_b,
                            const float* __restrict__ aw_b,
                            bf16* __restrict__ WeT,
                            bf16* __restrict__ Wcatb,
                            float* __restrict__ bcat2,
                            float* __restrict__ core) {
  const int bid = blockIdx.x;
  const int tid = threadIdx.x;

  if (bid < P_WCAT) {                    // ---- WeT[e][d] = embed_w[d][e] ----
    const int t = bid * 256 + tid;       // < 73728 exactly (288*256)
    const int e = t / 96;
    const int g = t - e * 96;            // d-group of 8
    bf16x8 o;
#pragma unroll
    for (int j = 0; j < 8; ++j)
      o[j] = (bf16)embed_w[(size_t)(g * 8 + j) * DM + e];
    *(bf16x8*)(WeT + (size_t)e * DM + g * 8) = o;
    return;
  }

  if (bid < P_BCAT) {                    // ---- Wcat_b cast/concat ----
    const int t = (bid - P_WCAT) * 256 + tid;   // < 86016 exactly (336*256)
    const int rr = t / 96;
    const int g  = t - rr * 96;
    const float* src = (rr < 768) ? value_w + (size_t)rr * DM
                     : (rr < 800) ? off_w + (size_t)(rr - 768) * DM
                     : (rr < 816) ? aw_w + (size_t)(rr - 800) * DM : nullptr;
    bf16x8 o;
    if (src) {
      const float4 f0 = *(const float4*)(src + g * 8);
      const float4 f1 = *(const float4*)(src + g * 8 + 4);
      o[0] = (bf16)f0.x; o[1] = (bf16)f0.y; o[2] = (bf16)f0.z; o[3] = (bf16)f0.w;
      o[4] = (bf16)f1.x; o[5] = (bf16)f1.y; o[6] = (bf16)f1.z; o[7] = (bf16)f1.w;
    } else {
#pragma unroll
      for (int j = 0; j < 8; ++j) o[j] = (bf16)0.f;
    }
    *(bf16x8*)(Wcatb + (size_t)rr * DM + g * 8) = o;
    return;
  }

  if (bid < P_ZERO) {                    // ---- bcat2 = Wcat @ embed_b + bias ----
    const int o = (bid - P_BCAT) * 256 + tid;   // 0..1023
    if (o < NCAT) {
      float bias_o = (o < 768) ? value_b[o]
                   : (o < 800) ? off_b[o - 768]
                   : (o < 816) ? aw_b[o - 800] : 0.f;
      float acc = 0.f;
      if (o < 816) {
        const float* wr = (o < 768) ? value_w + (size_t)o * DM
                        : (o < 800) ? off_w + (size_t)(o - 768) * DM
                        : aw_w + (size_t)(o - 800) * DM;
        const float4* w4p = (const float4*)wr;
        const float4* b4p = (const float4*)embed_b;
#pragma unroll 4
        for (int k = 0; k < DM / 4; ++k) {
          const float4 wv = w4p[k], bv = b4p[k];
          acc += wv.x * bv.x + wv.y * bv.y + wv.z * bv.z + wv.w * bv.w;
        }
      }
      bcat2[o] = acc + bias_o;
    }
    return;
  }

  // ---- zero core ----
  const int i = (bid - P_ZERO) * 256 + tid;
  f32x4 z = {0.f, 0.f, 0.f, 0.f};
  ((f32x4*)core)[i] = z;
}

// ---------------------------------------------------------------------------
// stage: NO __shared__ (im2col occupancy stays wave-limited at 8 blocks/CU).
// blocks [0,42):    fold-GEMM Wc = Wcat_b @ WeT^T via register MFMA fragments
// blocks [42,9450): im2col, one thread = 4 consecutive k of one row.
// ---------------------------------------------------------------------------
__global__ void stage_kernel(const float* __restrict__ x,
                             const bf16* __restrict__ Wcatb,
                             const bf16* __restrict__ WeT,
                             bf16* __restrict__ A,
                             bf16* __restrict__ Wc) {
  const int bid = blockIdx.x;
  const int tid = threadIdx.x;

  if (bid >= B_IM2COL) {                 // ---- im2col ----
    const int t   = (bid - B_IM2COL) * 256 + tid;  // < 12544*192 exactly
    const int row = t / 192;
    const int j   = t - row * 192;
    const int k   = j * 4;               // k = c*256 + p*16 + q, q%4==0
    const int c   = k >> 8;
    const int r   = k & 255;
    const int p   = r >> 4;
    const int q   = r & 15;
    const int n   = row / 196;
    const int lq  = row - n * 196;
    const int h   = lq / 14;
    const int w   = lq - h * 14;
    const float4 v = *(const float4*)(x +
        ((((size_t)n * 3 + c) * 224) + h * 16 + p) * 224 + w * 16 + q);
    bf16x4 o;
    o[0] = (bf16)v.x; o[1] = (bf16)v.y; o[2] = (bf16)v.z; o[3] = (bf16)v.w;
    *(bf16x4*)(A + (size_t)row * DM + k) = o;
    return;
  }

  // ---- fold-GEMM: Wc[o,e] = sum_d Wcat_b[o,d] * WeT[e,d] ----
  const int mT = bid / 6;                // 0..6  o-tile
  const int nT = bid - mT * 6;           // 0..5  e-tile
  const int oBase = mT * 128;
  const int eBase = nT * 128;
  const int wave = tid >> 6;
  const int lane = tid & 63;
  const int quad = lane >> 4;
  const int r16  = lane & 15;
  const int wm = wave & 1;
  const int wn = wave >> 1;

  const f32x4 zero = {0.f, 0.f, 0.f, 0.f};
  f32x4 acc[4][4];
#pragma unroll
  for (int mi = 0; mi < 4; ++mi)
#pragma unroll
    for (int ni = 0; ni < 4; ++ni) acc[mi][ni] = zero;

  const bf16* Ab = Wcatb + (size_t)(oBase + wm * 64 + r16) * DM + quad * 8;
  const bf16* Bb = WeT   + (size_t)(eBase + wn * 64 + r16) * DM + quad * 8;

#pragma unroll 2
  for (int kk = 0; kk < DM; kk += 32) {
    bf16x8 af[4], bfr[4];
#pragma unroll
    for (int mi = 0; mi < 4; ++mi)
      af[mi] = *(const bf16x8*)(Ab + (size_t)mi * 16 * DM + kk);
#pragma unroll
    for (int ni = 0; ni < 4; ++ni)
      bfr[ni] = *(const bf16x8*)(Bb + (size_t)ni * 16 * DM + kk);
#pragma unroll
    for (int mi = 0; mi < 4; ++mi)
#pragma unroll
      for (int ni = 0; ni < 4; ++ni)
        acc[mi][ni] = __builtin_amdgcn_mfma_f32_16x16x32_bf16(
            af[mi], bfr[ni], acc[mi][ni], 0, 0, 0);
  }

#pragma unroll
  for (int ni = 0; ni < 4; ++ni) {
    const int col = eBase + wn * 64 + ni * 16 + r16;
#pragma unroll
    for (int mi = 0; mi < 4; ++mi) {
      const int row0 = oBase + wm * 64 + mi * 16 + quad * 4;
#pragma unroll
      for (int rr = 0; rr < 4; ++rr)
        Wc[(size_t)(row0 + rr) * DM + col] = (bf16)acc[mi][ni][rr];
    }
  }
}

// ---------------------------------------------------------------------------
// gemm2_mixed: C = A[M,K]bf16 @ B[N,K]bf16^T + bias; epilogue splits columns:
//   col <  768 -> Vbuf bf16 [M,768];  col < 816 -> OA f32 [M,64];  else drop.
// 128x128 tile, BK=64, 256 threads (4 waves, 2x2), mfma_f32_16x16x32_bf16.
// == R9-exact version (R10's 64x128 regressed: halved MFMA/barrier, +50%
// staging traffic). XCD-chunked bijective swizzle (m204): each XCD owns a
// contiguous n-fast range so the 7 n-tiles of an A m-tile share one XCD L2.
// ---------------------------------------------------------------------------
__global__ void gemm2_mixed(const bf16* __restrict__ A, const bf16* __restrict__ B,
                            const float* __restrict__ bias,
                            bf16* __restrict__ Vb, float* __restrict__ OA,
                            int M, int N, int K) {
  __shared__ bf16 As[128 * 64];
  __shared__ bf16 Bs[128 * 64];

  const int tid  = threadIdx.x;
  const int wave = tid >> 6;
  const int lane = tid & 63;

  // ---- XCD-chunked swizzle (bijective for any nwg) ----
  const int p   = blockIdx.y * gridDim.x + blockIdx.x;   // physical linear id
  const int nwg = gridDim.x * gridDim.y;
  const int q   = nwg >> 3;
  const int r   = nwg & 7;
  const int xcd = p & 7;                 // HW round-robins workgroups % 8 XCDs
  const int jj  = p >> 3;
  const int L   = (xcd < r ? xcd * (q + 1) : r * (q + 1) + (xcd - r) * q) + jj;
  const int nT  = L % gridDim.x;         // n-fast: consecutive L share an A-tile
  const int mT  = L / gridDim.x;
  const int nBase = nT * 128;
  const int mBase = mT * 128;

  const int wm = wave & 1;
  const int wn = wave >> 1;
  const int quad = lane >> 4;
  const int r16  = lane & 15;

  const f32x4 zero = {0.f, 0.f, 0.f, 0.f};
  f32x4 acc[4][4];
#pragma unroll
  for (int mi = 0; mi < 4; ++mi)
#pragma unroll
    for (int ni = 0; ni < 4; ++ni) acc[mi][ni] = zero;

  const int srow = wave * 32 + (lane >> 3);
  const int scol = (lane & 7) * 8;
  const bf16* Ag = A + (size_t)(mBase + srow) * K + scol;
  const bf16* Bg = B + (size_t)(nBase + srow) * K + scol;
  bf16* Al = As + srow * 64 + scol;
  bf16* Bl = Bs + srow * 64 + scol;

  for (int kt = 0; kt < K; kt += 64) {
#pragma unroll
    for (int i = 0; i < 4; ++i) {
      gload_lds16(Ag + (size_t)(i * 8) * K + kt, Al + i * 8 * 64);
      gload_lds16(Bg + (size_t)(i * 8) * K + kt, Bl + i * 8 * 64);
    }
    __syncthreads();
#pragma unroll
    for (int kk = 0; kk < 64; kk += 32) {
      bf16x8 af[4], bfr[4];
#pragma unroll
      for (int mi = 0; mi < 4; ++mi)
        af[mi] = *(const bf16x8*)&As[(wm * 64 + mi * 16 + r16) * 64 + kk + quad * 8];
#pragma unroll
      for (int ni = 0; ni < 4; ++ni)
        bfr[ni] = *(const bf16x8*)&Bs[(wn * 64 + ni * 16 + r16) * 64 + kk + quad * 8];
#pragma unroll
      for (int mi = 0; mi < 4; ++mi)
#pragma unroll
        for (int ni = 0; ni < 4; ++ni)
          acc[mi][ni] = __builtin_amdgcn_mfma_f32_16x16x32_bf16(
              af[mi], bfr[ni], acc[mi][ni], 0, 0, 0);
    }
    __syncthreads();
  }

  // epilogue: C row = quad*4 + reg, col = lane&15 (m89/m91-verified layout)
#pragma unroll
  for (int ni = 0; ni < 4; ++ni) {
    const int col = nBase + wn * 64 + ni * 16 + r16;
    const float bv = bias[col];
#pragma unroll
    for (int mi = 0; mi < 4; ++mi) {
      const int row0 = mBase + wm * 64 + mi * 16 + quad * 4;
#pragma unroll
      for (int rr = 0; rr < 4; ++rr) {
        float v = acc[mi][ni][rr] + bv;
        int row = row0 + rr;
        if (col < 768) {
          Vb[(size_t)row * 768 + col] = (bf16)v;
        } else if (col < 816) {
          OA[(size_t)row * 64 + (col - 768)] = v;
        }
      }
    }
  }
}

// ---------------------------------------------------------------------------
// deform: grid (64, 49), block 192 (3 waves).
// Phase 1 (64 threads): per (lq_i, head, point) compute 4 combined
//   softmax*bilinear*validity weights + 4 clamped token indices -> LDS.
// Phase 2 (192 threads): thread = 4 consecutive channels, bf16x4 (8B)
//   corner loads -> 512B/wave-instr vs 128B scalar (R10 change, kept for
//   this round's A/B isolation).
// ---------------------------------------------------------------------------
__global__ void deform_kernel(const bf16* __restrict__ Vb,
                              const float* __restrict__ OA,
                              float* __restrict__ core) {
  __shared__ float s_w[64][4];
  __shared__ int   s_t[64][4];

  const int n   = blockIdx.x;
  const int lq0 = blockIdx.y * 4;
  const int tid = threadIdx.x;

  if (tid < 64) {
    const int i = tid >> 4;          // lq within group
    const int m = (tid >> 2) & 3;    // head
    const int p = tid & 3;           // point
    const int lq = lq0 + i;
    const float* row = OA + ((size_t)n * LQ + lq) * 64;

    const float l0 = row[32 + m * 4 + 0];
    const float l1 = row[32 + m * 4 + 1];
    const float l2 = row[32 + m * 4 + 2];
    const float l3 = row[32 + m * 4 + 3];
    const float mx = fmaxf(fmaxf(l0, l1), fmaxf(l2, l3));
    const float e0 = __expf(l0 - mx), e1 = __expf(l1 - mx);
    const float e2 = __expf(l2 - mx), e3 = __expf(l3 - mx);
    const float inv = 1.f / (e0 + e1 + e2 + e3);
    const float ep[4] = {e0, e1, e2, e3};
    const float ew = ep[p] * inv;

    const int h = lq / 14, w = lq - (lq / 14) * 14;
    // px = w*14/13 + offx - 0.5  (ref linspace(0,1,14), normalizer W=14)
    const float px = (float)w * (14.f / 13.f) - 0.5f + row[(m * 4 + p) * 2 + 0];
    const float py = (float)h * (14.f / 13.f) - 0.5f + row[(m * 4 + p) * 2 + 1];
    const float fx = floorf(px), fy = floorf(py);
    const int x0 = (int)fx, y0 = (int)fy;
    const float wx1 = px - fx, wy1 = py - fy;
    const float wx0 = 1.f - wx1, wy0 = 1.f - wy1;

    const bool vx0 = (x0 >= 0) & (x0 < 14);
    const bool vx1 = (x0 >= -1) & (x0 < 13);
    const bool vy0 = (y0 >= 0) & (y0 < 14);
    const bool vy1 = (y0 >= -1) & (y0 < 13);
    const int cx0 = min(max(x0, 0), 13),      cx1 = min(max(x0 + 1, 0), 13);
    const int cy0 = min(max(y0, 0), 13) * 14, cy1 = min(max(y0 + 1, 0), 13) * 14;

    s_w[tid][0] = (vx0 & vy0) ? ew * wx0 * wy0 : 0.f;
    s_w[tid][1] = (vx1 & vy0) ? ew * wx1 * wy0 : 0.f;
    s_w[tid][2] = (vx0 & vy1) ? ew * wx0 * wy1 : 0.f;
    s_w[tid][3] = (vx1 & vy1) ? ew * wx1 * wy1 : 0.f;
    s_t[tid][0] = cy0 + cx0;
    s_t[tid][1] = cy0 + cx1;
    s_t[tid][2] = cy1 + cx0;
    s_t[tid][3] = cy1 + cx1;
  }
  __syncthreads();

  const int ch = tid * 4;           // 0..764, 4 consecutive channels
  const int m  = tid / 48;          // head (uniform per 48-thread group)
  const bf16* vb = Vb + (size_t)n * LQ * 768 + ch;
  float a0 = 0.f, a1 = 0.f, a2 = 0.f, a3 = 0.f;
#pragma unroll
  for (int i = 0; i < 4; ++i) {
#pragma unroll
    for (int p = 0; p < 4; ++p) {
      const int e = i * 16 + m * 4 + p;
      const float4 w4 = *(const float4*)s_w[e];
      const int4   t4 = *(const int4*)s_t[e];
      const bf16x4 v0 = *(const bf16x4*)(vb + (size_t)t4.x * 768);
      const bf16x4 v1 = *(const bf16x4*)(vb + (size_t)t4.y * 768);
      const bf16x4 v2 = *(const bf16x4*)(vb + (size_t)t4.z * 768);
      const bf16x4 v3 = *(const bf16x4*)(vb + (size_t)t4.w * 768);
      a0 += w4.x * (float)v0[0] + w4.y * (float)v1[0]
          + w4.z * (float)v2[0] + w4.w * (float)v3[0];
      a1 += w4.x * (float)v0[1] + w4.y * (float)v1[1]
          + w4.z * (float)v2[1] + w4.w * (float)v3[1];
      a2 += w4.x * (float)v0[2] + w4.y * (float)v1[2]
          + w4.z * (float)v2[2] + w4.w * (float)v3[2];
      a3 += w4.x * (float)v0[3] + w4.y * (float)v1[3]
          + w4.z * (float)v2[3] + w4.w * (float)v3[3];
    }
  }
  float* cp = core + (size_t)n * DM + ch;
  atomicAdd(cp + 0, a0 * (1.f / 196.f));
  atomicAdd(cp + 1, a1 * (1.f / 196.f));
  atomicAdd(cp + 2, a2 * (1.f / 196.f));
  atomicAdd(cp + 3, a3 * (1.f / 196.f));
}

// ---------------------------------------------------------------------------
// small_linear_ks: out[n][d] = sum_k in[n][k] * W[d][k] + b[d]
// grid (N_IMG/4, DM/64), block 256 = 4 waves. 4 images/block share W reads;
// K split across the 4 waves, LDS cross-wave reduce. (R7: confirmed fix.)
// ---------------------------------------------------------------------------
__global__ void small_linear_ks(const float* __restrict__ in,
                                const float* __restrict__ W,
                                const float* __restrict__ b,
                                float* __restrict__ out) {
  __shared__ float s_in[4 * DM];           // 12 KB
  __shared__ float s_red[3][4][64];        // 3 KB
  const int tid = threadIdx.x;
  const int n0 = blockIdx.x * 4;
  const float4* src = (const float4*)(in + (size_t)n0 * DM);
#pragma unroll
  for (int i = 0; i < 3; ++i)              // 4*768 floats = 768 float4
    ((float4*)s_in)[tid + i * 256] = src[tid + i * 256];
  __syncthreads();

  const int dl = tid & 63;
  const int ks = tid >> 6;                 // wave id = K-quarter
  const int d  = blockIdx.y * 64 + dl;
  const int k0 = ks * (DM / 4);            // 192 floats per wave

  const float4* w4p = (const float4*)(W + (size_t)d * DM + k0);
  const float4* s0 = (const float4*)(s_in + k0);
  const float4* s1 = (const float4*)(s_in + DM + k0);
  const float4* s2 = (const float4*)(s_in + 2 * DM + k0);
  const float4* s3 = (const float4*)(s_in + 3 * DM + k0);
  float a0 = 0.f, a1 = 0.f, a2 = 0.f, a3 = 0.f;
#pragma unroll 8
  for (int k = 0; k < DM / 16; ++k) {      // 48 float4 iterations
    const float4 w = w4p[k];
    const float4 v0 = s0[k], v1 = s1[k], v2 = s2[k], v3 = s3[k];
    a0 += w.x * v0.x + w.y * v0.y + w.z * v0.z + w.w * v0.w;
    a1 += w.x * v1.x + w.y * v1.y + w.z * v1.z + w.w * v1.w;
    a2 += w.x * v2.x + w.y * v2.y + w.z * v2.z + w.w * v2.w;
    a3 += w.x * v3.x + w.y * v3.y + w.z * v3.z + w.w * v3.w;
  }

  if (ks > 0) {
    s_red[ks - 1][0][dl] = a0;
    s_red[ks - 1][1][dl] = a1;
    s_red[ks - 1][2][dl] = a2;
    s_red[ks - 1][3][dl] = a3;
  }
  __syncthreads();
  if (ks == 0) {
#pragma unroll
    for (int w = 0; w < 3; ++w) {
      a0 += s_red[w][0][dl];
      a1 += s_red[w][1][dl];
      a2 += s_red[w][2][dl];
      a3 += s_red[w][3][dl];
    }
    const float bv = b[d];
    out[(size_t)(n0 + 0) * DM + d] = a0 + bv;
    out[(size_t)(n0 + 1) * DM + d] = a1 + bv;
    out[(size_t)(n0 + 2) * DM + d] = a2 + bv;
    out[(size_t)(n0 + 3) * DM + d] = a3 + bv;
  }
}

// ---------------------------------------------------------------------------
extern "C" void kernel_launch(void* const* d_in, const int* in_sizes, int n_in,
                              void* d_out, int out_size, void* d_ws, size_t ws_size,
                              hipStream_t stream) {
  const float* x       = (const float*)d_in[0];
  const float* embed_w = (const float*)d_in[1];
  const float* embed_b = (const float*)d_in[2];
  const float* value_w = (const float*)d_in[3];
  const float* value_b = (const float*)d_in[4];
  const float* off_w   = (const float*)d_in[5];
  const float* off_b   = (const float*)d_in[6];
  const float* aw_w    = (const float*)d_in[7];
  const float* aw_b    = (const float*)d_in[8];
  const float* outp_w  = (const float*)d_in[9];
  const float* outp_b  = (const float*)d_in[10];
  const float* proj_w  = (const float*)d_in[11];
  const float* proj_b  = (const float*)d_in[12];
  float* out = (float*)d_out;

  char* ws = (char*)d_ws;
  bf16*  A      = (bf16*)(ws + OFF_A);
  bf16*  Wc     = (bf16*)(ws + OFF_WC);
  float* bcat2  = (float*)(ws + OFF_BCAT);
  bf16*  Vbuf   = (bf16*)(ws + OFF_VBUF);
  float* OA     = (float*)(ws + OFF_OA);
  float* core   = (float*)(ws + OFF_CORE);
  float* pooled = (float*)(ws + OFF_POOL);
  bf16*  Wcatb  = (bf16*)(ws + OFF_WCATB);
  bf16*  WeT    = (bf16*)(ws + OFF_WET);

  prep_kernel<<<dim3(PREP_GRID), dim3(256), 0, stream>>>(
      embed_w, embed_b, value_w, off_w, aw_w, value_b, off_b, aw_b,
      WeT, Wcatb, bcat2, core);

  stage_kernel<<<dim3(STAGE_GRID), dim3(256), 0, stream>>>(
      x, Wcatb, WeT, A, Wc);

  gemm2_mixed<<<dim3(NCAT / 128, M_ROWS / 128), dim3(256), 0, stream>>>(
      A, Wc, bcat2, Vbuf, OA, M_ROWS, NCAT, DM);

  deform_kernel<<<dim3(N_IMG, 49), dim3(192), 0, stream>>>(Vbuf, OA, core);

  small_linear_ks<<<dim3(N_IMG / 4, DM / 64), dim3(256), 0, stream>>>(
      core, outp_w, outp_b, pooled);
  small_linear_ks<<<dim3(N_IMG / 4, DM / 64), dim3(256), 0, stream>>>(
      pooled, proj_w, proj_b, out);
}

// Round 14
// 231.391 us; speedup vs baseline: 1.1019x; 1.0663x over previous
//
#include <hip/hip_runtime.h>
#include <hip/hip_bf16.h>

// ---------------------------------------------------------------------------
// DeformableSpatialEncoder on MI355X (gfx950)
//
// Pipeline (N=64 images, Lq=196 tokens, D=768, heads=4, Dh=192, points=4):
//   0. prep:   WeT bf16 = embed_w^T; Wcat_b bf16 concat; bcat2; zero core.
//   1. stage:  blocks [0,42):   LDS-free fold-GEMM Wc[896,768] = Wcat_b @ WeT^T
//              blocks [42,9450): im2col x -> A bf16 [12544,768]
//      Folding identity: cat = (A@We^T+be)@Wcat^T+bcat = A@(Wcat·We)^T + (...)
//   2. gemm2:  value -> Vbuf bf16; off/aw -> OA f32.
//              128x128 tile + XCD-chunked swizzle (R13 profile: FETCH 21.2MB
//              == ideal, swizzle confirmed).
//   3. deform: R9-EXACT scalar version: grid (64,49,3), block 256, thread =
//              one channel, 64 scalar bf16 gathers. (R13 A/B: deform-vec
//              showed no benefit in two tries and a suspected ~8us cost on
//              a ~3%-slower container; reverting to the measured-best 231.9us
//              configuration for attribution closure.)
//   4. pooled = core_mean @ outp_w^T + outp_b
//   5. final  = pooled @ proj_w^T + proj_b -> d_out
//      4/5 use small_linear_ks (R7: confirmed fix).
// ---------------------------------------------------------------------------

using bf16 = __bf16;
typedef bf16  bf16x4 __attribute__((ext_vector_type(4)));
typedef bf16  bf16x8 __attribute__((ext_vector_type(8)));
typedef float f32x4  __attribute__((ext_vector_type(4)));

#define N_IMG   64
#define LQ      196
#define DM      768
#define NH      4
#define DH      192
#define M_ROWS  (N_IMG * LQ)        // 12544
#define NCAT    896                 // 768 value + 32 off + 16 aw + 80 pad

// prep grid layout
#define P_WET    0                  // 288 blocks: WeT transpose-cast
#define P_WCAT   288                // 336 blocks: Wcat_b cast/concat
#define P_BCAT   624                // 4 blocks
#define P_ZERO   628                // 48 blocks
#define PREP_GRID 676

// stage grid layout
#define B_WGEMM   0                 // 42 blocks: 7 (o-tiles) x 6 (e-tiles)
#define B_IM2COL  42                // 9408 blocks
#define STAGE_GRID (B_IM2COL + 9408)

// ---- workspace layout (bytes, all 256-aligned) ----
#define OFF_A     ((size_t)0)                      // 12544*768*2 = 19267584
#define OFF_WC    (OFF_A     + 19267584)           // 896*768*2   = 1376256
#define OFF_BCAT  (OFF_WC    + 1376256)            // 4096
#define OFF_VBUF  (OFF_BCAT  + 4096)               // 12544*768*2 = 19267584
#define OFF_OA    (OFF_VBUF  + 19267584)           // 12544*64*4  = 3211264
#define OFF_CORE  (OFF_OA    + 3211264)            // 196608
#define OFF_POOL  (OFF_CORE  + 196608)             // 196608
#define OFF_WCATB (OFF_POOL  + 196608)             // 896*768*2   = 1376256
#define OFF_WET   (OFF_WCATB + 1376256)            // 768*768*2   = 1179648

__device__ __forceinline__ void gload_lds16(const bf16* g, bf16* l) {
#if __has_builtin(__builtin_amdgcn_global_load_lds)
  __builtin_amdgcn_global_load_lds(
      (const __attribute__((address_space(1))) void*)g,
      (__attribute__((address_space(3))) void*)l, 16, 0, 0);
#else
  *(bf16x8*)l = *(const bf16x8*)g;
#endif
}

// ---------------------------------------------------------------------------
// prep: WeT transpose-cast, Wcat_b cast, bcat2, core zero.
// ---------------------------------------------------------------------------
__global__ void prep_kernel(const float* __restrict__ embed_w,
                            const float* __restrict__ embed_b,
                            const float* __restrict__ value_w,
                            const float* __restrict__ off_w,
                            const float* __restrict__ aw_w,
                            const float* __restrict__ value_b,
                            const float* __restrict__ off_b,
                            const float* __restrict__ aw_b,
                            bf16* __restrict__ WeT,
                            bf16* __restrict__ Wcatb,
                            float* __restrict__ bcat2,
                            float* __restrict__ core) {
  const int bid = blockIdx.x;
  const int tid = threadIdx.x;

  if (bid < P_WCAT) {                    // ---- WeT[e][d] = embed_w[d][e] ----
    const int t = bid * 256 + tid;       // < 73728 exactly (288*256)
    const int e = t / 96;
    const int g = t - e * 96;            // d-group of 8
    bf16x8 o;
#pragma unroll
    for (int j = 0; j < 8; ++j)
      o[j] = (bf16)embed_w[(size_t)(g * 8 + j) * DM + e];
    *(bf16x8*)(WeT + (size_t)e * DM + g * 8) = o;
    return;
  }

  if (bid < P_BCAT) {                    // ---- Wcat_b cast/concat ----
    const int t = (bid - P_WCAT) * 256 + tid;   // < 86016 exactly (336*256)
    const int rr = t / 96;
    const int g  = t - rr * 96;
    const float* src = (rr < 768) ? value_w + (size_t)rr * DM
                     : (rr < 800) ? off_w + (size_t)(rr - 768) * DM
                     : (rr < 816) ? aw_w + (size_t)(rr - 800) * DM : nullptr;
    bf16x8 o;
    if (src) {
      const float4 f0 = *(const float4*)(src + g * 8);
      const float4 f1 = *(const float4*)(src + g * 8 + 4);
      o[0] = (bf16)f0.x; o[1] = (bf16)f0.y; o[2] = (bf16)f0.z; o[3] = (bf16)f0.w;
      o[4] = (bf16)f1.x; o[5] = (bf16)f1.y; o[6] = (bf16)f1.z; o[7] = (bf16)f1.w;
    } else {
#pragma unroll
      for (int j = 0; j < 8; ++j) o[j] = (bf16)0.f;
    }
    *(bf16x8*)(Wcatb + (size_t)rr * DM + g * 8) = o;
    return;
  }

  if (bid < P_ZERO) {                    // ---- bcat2 = Wcat @ embed_b + bias ----
    const int o = (bid - P_BCAT) * 256 + tid;   // 0..1023
    if (o < NCAT) {
      float bias_o = (o < 768) ? value_b[o]
                   : (o < 800) ? off_b[o - 768]
                   : (o < 816) ? aw_b[o - 800] : 0.f;
      float acc = 0.f;
      if (o < 816) {
        const float* wr = (o < 768) ? value_w + (size_t)o * DM
                        : (o < 800) ? off_w + (size_t)(o - 768) * DM
                        : aw_w + (size_t)(o - 800) * DM;
        const float4* w4p = (const float4*)wr;
        const float4* b4p = (const float4*)embed_b;
#pragma unroll 4
        for (int k = 0; k < DM / 4; ++k) {
          const float4 wv = w4p[k], bv = b4p[k];
          acc += wv.x * bv.x + wv.y * bv.y + wv.z * bv.z + wv.w * bv.w;
        }
      }
      bcat2[o] = acc + bias_o;
    }
    return;
  }

  // ---- zero core ----
  const int i = (bid - P_ZERO) * 256 + tid;
  f32x4 z = {0.f, 0.f, 0.f, 0.f};
  ((f32x4*)core)[i] = z;
}

// ---------------------------------------------------------------------------
// stage: NO __shared__ (im2col occupancy stays wave-limited at 8 blocks/CU).
// blocks [0,42):    fold-GEMM Wc = Wcat_b @ WeT^T via register MFMA fragments
// blocks [42,9450): im2col, one thread = 4 consecutive k of one row.
// ---------------------------------------------------------------------------
__global__ void stage_kernel(const float* __restrict__ x,
                             const bf16* __restrict__ Wcatb,
                             const bf16* __restrict__ WeT,
                             bf16* __restrict__ A,
                             bf16* __restrict__ Wc) {
  const int bid = blockIdx.x;
  const int tid = threadIdx.x;

  if (bid >= B_IM2COL) {                 // ---- im2col ----
    const int t   = (bid - B_IM2COL) * 256 + tid;  // < 12544*192 exactly
    const int row = t / 192;
    const int j   = t - row * 192;
    const int k   = j * 4;               // k = c*256 + p*16 + q, q%4==0
    const int c   = k >> 8;
    const int r   = k & 255;
    const int p   = r >> 4;
    const int q   = r & 15;
    const int n   = row / 196;
    const int lq  = row - n * 196;
    const int h   = lq / 14;
    const int w   = lq - h * 14;
    const float4 v = *(const float4*)(x +
        ((((size_t)n * 3 + c) * 224) + h * 16 + p) * 224 + w * 16 + q);
    bf16x4 o;
    o[0] = (bf16)v.x; o[1] = (bf16)v.y; o[2] = (bf16)v.z; o[3] = (bf16)v.w;
    *(bf16x4*)(A + (size_t)row * DM + k) = o;
    return;
  }

  // ---- fold-GEMM: Wc[o,e] = sum_d Wcat_b[o,d] * WeT[e,d] ----
  const int mT = bid / 6;                // 0..6  o-tile
  const int nT = bid - mT * 6;           // 0..5  e-tile
  const int oBase = mT * 128;
  const int eBase = nT * 128;
  const int wave = tid >> 6;
  const int lane = tid & 63;
  const int quad = lane >> 4;
  const int r16  = lane & 15;
  const int wm = wave & 1;
  const int wn = wave >> 1;

  const f32x4 zero = {0.f, 0.f, 0.f, 0.f};
  f32x4 acc[4][4];
#pragma unroll
  for (int mi = 0; mi < 4; ++mi)
#pragma unroll
    for (int ni = 0; ni < 4; ++ni) acc[mi][ni] = zero;

  const bf16* Ab = Wcatb + (size_t)(oBase + wm * 64 + r16) * DM + quad * 8;
  const bf16* Bb = WeT   + (size_t)(eBase + wn * 64 + r16) * DM + quad * 8;

#pragma unroll 2
  for (int kk = 0; kk < DM; kk += 32) {
    bf16x8 af[4], bfr[4];
#pragma unroll
    for (int mi = 0; mi < 4; ++mi)
      af[mi] = *(const bf16x8*)(Ab + (size_t)mi * 16 * DM + kk);
#pragma unroll
    for (int ni = 0; ni < 4; ++ni)
      bfr[ni] = *(const bf16x8*)(Bb + (size_t)ni * 16 * DM + kk);
#pragma unroll
    for (int mi = 0; mi < 4; ++mi)
#pragma unroll
      for (int ni = 0; ni < 4; ++ni)
        acc[mi][ni] = __builtin_amdgcn_mfma_f32_16x16x32_bf16(
            af[mi], bfr[ni], acc[mi][ni], 0, 0, 0);
  }

#pragma unroll
  for (int ni = 0; ni < 4; ++ni) {
    const int col = eBase + wn * 64 + ni * 16 + r16;
#pragma unroll
    for (int mi = 0; mi < 4; ++mi) {
      const int row0 = oBase + wm * 64 + mi * 16 + quad * 4;
#pragma unroll
      for (int rr = 0; rr < 4; ++rr)
        Wc[(size_t)(row0 + rr) * DM + col] = (bf16)acc[mi][ni][rr];
    }
  }
}

// ---------------------------------------------------------------------------
// gemm2_mixed: C = A[M,K]bf16 @ B[N,K]bf16^T + bias; epilogue splits columns:
//   col <  768 -> Vbuf bf16 [M,768];  col < 816 -> OA f32 [M,64];  else drop.
// 128x128 tile, BK=64, 256 threads (4 waves, 2x2), mfma_f32_16x16x32_bf16.
// XCD-chunked bijective swizzle (m204): each XCD owns a contiguous n-fast
// range so the 7 n-tiles of an A m-tile share one XCD L2 (R13 profile:
// FETCH 21.2MB == ideal, confirmed).
// ---------------------------------------------------------------------------
__global__ void gemm2_mixed(const bf16* __restrict__ A, const bf16* __restrict__ B,
                            const float* __restrict__ bias,
                            bf16* __restrict__ Vb, float* __restrict__ OA,
                            int M, int N, int K) {
  __shared__ bf16 As[128 * 64];
  __shared__ bf16 Bs[128 * 64];

  const int tid  = threadIdx.x;
  const int wave = tid >> 6;
  const int lane = tid & 63;

  // ---- XCD-chunked swizzle (bijective for any nwg) ----
  const int p   = blockIdx.y * gridDim.x + blockIdx.x;   // physical linear id
  const int nwg = gridDim.x * gridDim.y;
  const int q   = nwg >> 3;
  const int r   = nwg & 7;
  const int xcd = p & 7;                 // HW round-robins workgroups % 8 XCDs
  const int jj  = p >> 3;
  const int L   = (xcd < r ? xcd * (q + 1) : r * (q + 1) + (xcd - r) * q) + jj;
  const int nT  = L % gridDim.x;         // n-fast: consecutive L share an A-tile
  const int mT  = L / gridDim.x;
  const int nBase = nT * 128;
  const int mBase = mT * 128;

  const int wm = wave & 1;
  const int wn = wave >> 1;
  const int quad = lane >> 4;
  const int r16  = lane & 15;

  const f32x4 zero = {0.f, 0.f, 0.f, 0.f};
  f32x4 acc[4][4];
#pragma unroll
  for (int mi = 0; mi < 4; ++mi)
#pragma unroll
    for (int ni = 0; ni < 4; ++ni) acc[mi][ni] = zero;

  const int srow = wave * 32 + (lane >> 3);
  const int scol = (lane & 7) * 8;
  const bf16* Ag = A + (size_t)(mBase + srow) * K + scol;
  const bf16* Bg = B + (size_t)(nBase + srow) * K + scol;
  bf16* Al = As + srow * 64 + scol;
  bf16* Bl = Bs + srow * 64 + scol;

  for (int kt = 0; kt < K; kt += 64) {
#pragma unroll
    for (int i = 0; i < 4; ++i) {
      gload_lds16(Ag + (size_t)(i * 8) * K + kt, Al + i * 8 * 64);
      gload_lds16(Bg + (size_t)(i * 8) * K + kt, Bl + i * 8 * 64);
    }
    __syncthreads();
#pragma unroll
    for (int kk = 0; kk < 64; kk += 32) {
      bf16x8 af[4], bfr[4];
#pragma unroll
      for (int mi = 0; mi < 4; ++mi)
        af[mi] = *(const bf16x8*)&As[(wm * 64 + mi * 16 + r16) * 64 + kk + quad * 8];
#pragma unroll
      for (int ni = 0; ni < 4; ++ni)
        bfr[ni] = *(const bf16x8*)&Bs[(wn * 64 + ni * 16 + r16) * 64 + kk + quad * 8];
#pragma unroll
      for (int mi = 0; mi < 4; ++mi)
#pragma unroll
        for (int ni = 0; ni < 4; ++ni)
          acc[mi][ni] = __builtin_amdgcn_mfma_f32_16x16x32_bf16(
              af[mi], bfr[ni], acc[mi][ni], 0, 0, 0);
    }
    __syncthreads();
  }

  // epilogue: C row = quad*4 + reg, col = lane&15 (m89/m91-verified layout)
#pragma unroll
  for (int ni = 0; ni < 4; ++ni) {
    const int col = nBase + wn * 64 + ni * 16 + r16;
    const float bv = bias[col];
#pragma unroll
    for (int mi = 0; mi < 4; ++mi) {
      const int row0 = mBase + wm * 64 + mi * 16 + quad * 4;
#pragma unroll
      for (int rr = 0; rr < 4; ++rr) {
        float v = acc[mi][ni][rr] + bv;
        int row = row0 + rr;
        if (col < 768) {
          Vb[(size_t)row * 768 + col] = (bf16)v;
        } else if (col < 816) {
          OA[(size_t)row * 64 + (col - 768)] = v;
        }
      }
    }
  }
}

// ---------------------------------------------------------------------------
// deform: grid (64, 49, 3), block 256.  (R9-exact scalar version.)
// Phase 1 (64 threads): per (lq_i, head, point) compute 4 combined
//   softmax*bilinear*validity weights + 4 clamped token indices -> LDS.
// Phase 2 (256 threads): thread = channel; 64 unconditional bf16 gathers
//   from Vbuf, weights broadcast from LDS (waves are head-uniform).
// ---------------------------------------------------------------------------
__global__ void deform_kernel(const bf16* __restrict__ Vb,
                              const float* __restrict__ OA,
                              float* __restrict__ core) {
  __shared__ float s_w[64][4];
  __shared__ int   s_t[64][4];

  const int n   = blockIdx.x;
  const int lq0 = blockIdx.y * 4;
  const int z   = blockIdx.z;
  const int tid = threadIdx.x;

  if (tid < 64) {
    const int i = tid >> 4;          // lq within group
    const int m = (tid >> 2) & 3;    // head
    const int p = tid & 3;           // point
    const int lq = lq0 + i;
    const float* row = OA + ((size_t)n * LQ + lq) * 64;

    const float l0 = row[32 + m * 4 + 0];
    const float l1 = row[32 + m * 4 + 1];
    const float l2 = row[32 + m * 4 + 2];
    const float l3 = row[32 + m * 4 + 3];
    const float mx = fmaxf(fmaxf(l0, l1), fmaxf(l2, l3));
    const float e0 = __expf(l0 - mx), e1 = __expf(l1 - mx);
    const float e2 = __expf(l2 - mx), e3 = __expf(l3 - mx);
    const float inv = 1.f / (e0 + e1 + e2 + e3);
    const float ep[4] = {e0, e1, e2, e3};
    const float ew = ep[p] * inv;

    const int h = lq / 14, w = lq - (lq / 14) * 14;
    // px = w*14/13 + offx - 0.5  (ref linspace(0,1,14), normalizer W=14)
    const float px = (float)w * (14.f / 13.f) - 0.5f + row[(m * 4 + p) * 2 + 0];
    const float py = (float)h * (14.f / 13.f) - 0.5f + row[(m * 4 + p) * 2 + 1];
    const float fx = floorf(px), fy = floorf(py);
    const int x0 = (int)fx, y0 = (int)fy;
    const float wx1 = px - fx, wy1 = py - fy;
    const float wx0 = 1.f - wx1, wy0 = 1.f - wy1;

    const bool vx0 = (x0 >= 0) & (x0 < 14);
    const bool vx1 = (x0 >= -1) & (x0 < 13);
    const bool vy0 = (y0 >= 0) & (y0 < 14);
    const bool vy1 = (y0 >= -1) & (y0 < 13);
    const int cx0 = min(max(x0, 0), 13),      cx1 = min(max(x0 + 1, 0), 13);
    const int cy0 = min(max(y0, 0), 13) * 14, cy1 = min(max(y0 + 1, 0), 13) * 14;

    s_w[tid][0] = (vx0 & vy0) ? ew * wx0 * wy0 : 0.f;
    s_w[tid][1] = (vx1 & vy0) ? ew * wx1 * wy0 : 0.f;
    s_w[tid][2] = (vx0 & vy1) ? ew * wx0 * wy1 : 0.f;
    s_w[tid][3] = (vx1 & vy1) ? ew * wx1 * wy1 : 0.f;
    s_t[tid][0] = cy0 + cx0;
    s_t[tid][1] = cy0 + cx1;
    s_t[tid][2] = cy1 + cx0;
    s_t[tid][3] = cy1 + cx1;
  }
  __syncthreads();

  const int ch = z * 256 + tid;     // 0..767 (value column)
  const int m  = ch / DH;           // head (wave-uniform)
  const bf16* vb = Vb + (size_t)n * LQ * 768 + ch;
  float acc = 0.f;
#pragma unroll
  for (int i = 0; i < 4; ++i) {
#pragma unroll
    for (int p = 0; p < 4; ++p) {
      const int e = i * 16 + m * 4 + p;
      const float4 w4 = *(const float4*)s_w[e];
      const int4   t4 = *(const int4*)s_t[e];
      acc += w4.x * (float)vb[(size_t)t4.x * 768];
      acc += w4.y * (float)vb[(size_t)t4.y * 768];
      acc += w4.z * (float)vb[(size_t)t4.z * 768];
      acc += w4.w * (float)vb[(size_t)t4.w * 768];
    }
  }
  atomicAdd(&core[(size_t)n * DM + ch], acc * (1.f / 196.f));
}

// ---------------------------------------------------------------------------
// small_linear_ks: out[n][d] = sum_k in[n][k] * W[d][k] + b[d]
// grid (N_IMG/4, DM/64), block 256 = 4 waves. 4 images/block share W reads;
// K split across the 4 waves, LDS cross-wave reduce. (R7: confirmed fix.)
// ---------------------------------------------------------------------------
__global__ void small_linear_ks(const float* __restrict__ in,
                                const float* __restrict__ W,
                                const float* __restrict__ b,
                                float* __restrict__ out) {
  __shared__ float s_in[4 * DM];           // 12 KB
  __shared__ float s_red[3][4][64];        // 3 KB
  const int tid = threadIdx.x;
  const int n0 = blockIdx.x * 4;
  const float4* src = (const float4*)(in + (size_t)n0 * DM);
#pragma unroll
  for (int i = 0; i < 3; ++i)              // 4*768 floats = 768 float4
    ((float4*)s_in)[tid + i * 256] = src[tid + i * 256];
  __syncthreads();

  const int dl = tid & 63;
  const int ks = tid >> 6;                 // wave id = K-quarter
  const int d  = blockIdx.y * 64 + dl;
  const int k0 = ks * (DM / 4);            // 192 floats per wave

  const float4* w4p = (const float4*)(W + (size_t)d * DM + k0);
  const float4* s0 = (const float4*)(s_in + k0);
  const float4* s1 = (const float4*)(s_in + DM + k0);
  const float4* s2 = (const float4*)(s_in + 2 * DM + k0);
  const float4* s3 = (const float4*)(s_in + 3 * DM + k0);
  float a0 = 0.f, a1 = 0.f, a2 = 0.f, a3 = 0.f;
#pragma unroll 8
  for (int k = 0; k < DM / 16; ++k) {      // 48 float4 iterations
    const float4 w = w4p[k];
    const float4 v0 = s0[k], v1 = s1[k], v2 = s2[k], v3 = s3[k];
    a0 += w.x * v0.x + w.y * v0.y + w.z * v0.z + w.w * v0.w;
    a1 += w.x * v1.x + w.y * v1.y + w.z * v1.z + w.w * v1.w;
    a2 += w.x * v2.x + w.y * v2.y + w.z * v2.z + w.w * v2.w;
    a3 += w.x * v3.x + w.y * v3.y + w.z * v3.z + w.w * v3.w;
  }

  if (ks > 0) {
    s_red[ks - 1][0][dl] = a0;
    s_red[ks - 1][1][dl] = a1;
    s_red[ks - 1][2][dl] = a2;
    s_red[ks - 1][3][dl] = a3;
  }
  __syncthreads();
  if (ks == 0) {
#pragma unroll
    for (int w = 0; w < 3; ++w) {
      a0 += s_red[w][0][dl];
      a1 += s_red[w][1][dl];
      a2 += s_red[w][2][dl];
      a3 += s_red[w][3][dl];
    }
    const float bv = b[d];
    out[(size_t)(n0 + 0) * DM + d] = a0 + bv;
    out[(size_t)(n0 + 1) * DM + d] = a1 + bv;
    out[(size_t)(n0 + 2) * DM + d] = a2 + bv;
    out[(size_t)(n0 + 3) * DM + d] = a3 + bv;
  }
}

// ---------------------------------------------------------------------------
extern "C" void kernel_launch(void* const* d_in, const int* in_sizes, int n_in,
                              void* d_out, int out_size, void* d_ws, size_t ws_size,
                              hipStream_t stream) {
  const float* x       = (const float*)d_in[0];
  const float* embed_w = (const float*)d_in[1];
  const float* embed_b = (const float*)d_in[2];
  const float* value_w = (const float*)d_in[3];
  const float* value_b = (const float*)d_in[4];
  const float* off_w   = (const float*)d_in[5];
  const float* off_b   = (const float*)d_in[6];
  const float* aw_w    = (const float*)d_in[7];
  const float* aw_b    = (const float*)d_in[8];
  const float* outp_w  = (const float*)d_in[9];
  const float* outp_b  = (const float*)d_in[10];
  const float* proj_w  = (const float*)d_in[11];
  const float* proj_b  = (const float*)d_in[12];
  float* out = (float*)d_out;

  char* ws = (char*)d_ws;
  bf16*  A      = (bf16*)(ws + OFF_A);
  bf16*  Wc     = (bf16*)(ws + OFF_WC);
  float* bcat2  = (float*)(ws + OFF_BCAT);
  bf16*  Vbuf   = (bf16*)(ws + OFF_VBUF);
  float* OA     = (float*)(ws + OFF_OA);
  float* core   = (float*)(ws + OFF_CORE);
  float* pooled = (float*)(ws + OFF_POOL);
  bf16*  Wcatb  = (bf16*)(ws + OFF_WCATB);
  bf16*  WeT    = (bf16*)(ws + OFF_WET);

  prep_kernel<<<dim3(PREP_GRID), dim3(256), 0, stream>>>(
      embed_w, embed_b, value_w, off_w, aw_w, value_b, off_b, aw_b,
      WeT, Wcatb, bcat2, core);

  stage_kernel<<<dim3(STAGE_GRID), dim3(256), 0, stream>>>(
      x, Wcatb, WeT, A, Wc);

  gemm2_mixed<<<dim3(NCAT / 128, M_ROWS / 128), dim3(256), 0, stream>>>(
      A, Wc, bcat2, Vbuf, OA, M_ROWS, NCAT, DM);

  deform_kernel<<<dim3(N_IMG, 49, 3), dim3(256), 0, stream>>>(Vbuf, OA, core);

  small_linear_ks<<<dim3(N_IMG / 4, DM / 64), dim3(256), 0, stream>>>(
      core, outp_w, outp_b, pooled);
  small_linear_ks<<<dim3(N_IMG / 4, DM / 64), dim3(256), 0, stream>>>(
      pooled, proj_w, proj_b, out);
}